// Round 6
// baseline (361.719 us; speedup 1.0000x reference)
//
#include <hip/hip_runtime.h>
#include <hip/hip_bf16.h>

// Problem constants
static constexpr int Bn = 8, Cn = 128, Hn = 64, Wn = 64, Con = 128;
static constexpr int KKn = 9, DGn = 2, Cgn = 64;
static constexpr int HOn = 64, WOn = 64;
static constexpr int PITCH = 72;     // bf16 row pitch for MFMA LDS/global tiles

typedef short short8 __attribute__((ext_vector_type(8)));
typedef float f32x4  __attribute__((ext_vector_type(4)));

__device__ __forceinline__ unsigned short f2bf(float f) {
    unsigned u = __float_as_uint(f);
    u += 0x7fff + ((u >> 16) & 1);          // round-to-nearest-even
    return (unsigned short)(u >> 16);
}
__device__ __forceinline__ float bf2f(unsigned short h) {
    return __uint_as_float(((unsigned)h) << 16);
}

// ---------------------------------------------------------------------------
// Kernel 0: main weight [Co,C,3,3] fp32 -> bf16, layout wt[gk][oc][c] with
// c padded to PITCH=72 (pad = 0). 18*128*72 = 165888 elems, grid 648x256.
// ---------------------------------------------------------------------------
__global__ __launch_bounds__(256) void wt_transpose(const float* __restrict__ w,
                                                    unsigned short* __restrict__ wt) {
    int e  = blockIdx.x * 256 + threadIdx.x;     // [0, 165888)
    int gk = e / (128 * PITCH);
    int r  = e - gk * (128 * PITCH);
    int oc = r / PITCH;
    int c  = r - oc * PITCH;
    int g  = gk / 9, k = gk - g * 9;
    float v = (c < Cgn) ? w[((size_t)oc * Cn + g * Cgn + c) * KKn + k] : 0.f;
    wt[e] = f2bf(v);
}

// ---------------------------------------------------------------------------
// Kernel 0b: pack offset weights: owp[tr][c][28], q = j*9+k (27 used, 1 pad).
// ---------------------------------------------------------------------------
__global__ __launch_bounds__(256) void ow_pack(const float* __restrict__ ow,
                                               float* __restrict__ owp) {
    int e  = blockIdx.x * 256 + threadIdx.x;     // [0, 32256)
    if (e >= 18 * 64 * 28) return;
    int tr = e / (64 * 28);
    int r  = e - tr * (64 * 28);
    int c  = r / 28;
    int q  = r - c * 28;
    float v = 0.f;
    if (q < 27) {
        int j = q / 9, k = q - j * 9;
        int oc = tr * 3 + j;
        v = ow[((size_t)oc * Cgn + c) * KKn + k];
    }
    owp[e] = v;
}

// ---------------------------------------------------------------------------
// Kernel 1: grouped offset conv, wo-quad vectorized. Thread = (ho, 4-wo quad):
// per c-iter 9 aligned float4 loads (12-float row segments) -> 108 FMA into
// 12 accumulators (4 pos x 3 oc). Same FMA order as R3 (bit-exact).
// 1-D grid 576 = 8b x 18tr x 4 strips(16 rows), XCD swizzle b = id & 7.
// ---------------------------------------------------------------------------
__global__ __launch_bounds__(256) void offset_conv(const float* __restrict__ x,
                                                   const float* __restrict__ owp,
                                                   const float* __restrict__ ob,
                                                   unsigned short* __restrict__ om) {
    const int id = blockIdx.x;                   // [0, 576)
    const int b  = id & 7;
    const int r  = id >> 3;                      // [0, 72)
    const int tr = r % 18;                       // oc triple
    const int st = r / 18;                       // 16-row strip [0,4)
    const int t  = threadIdx.x;
    const int q  = t & 15;                       // wo quad (4 cols)
    const int hl = t >> 4;                       // row in strip [0,16)
    const int ho = st * 16 + hl;
    const int g  = tr / 9;                       // conv group

    const float* wp = owp + (size_t)tr * 64 * 28;
    float acc[4][3];
#pragma unroll
    for (int j = 0; j < 4; ++j)
#pragma unroll
        for (int o = 0; o < 3; ++o) acc[j][o] = ob[tr * 3 + o];

    const float* xb = x + ((size_t)b * Cn + g * Cgn) * (Hn * Wn);
    const int iy0 = ho - 2, iy1 = ho, iy2 = ho + 2;
    const bool vy0 = iy0 >= 0, vy2 = iy2 < Hn;
    const bool vq0 = q > 0, vq2 = q < 15;
    const float4 z4 = {0.f, 0.f, 0.f, 0.f};

    for (int c = 0; c < Cgn; ++c) {
        const float* xc = xb + (size_t)c * (Hn * Wn);
        // row segments: cols 4q-4 .. 4q+7 (12 floats per row)
        float sg[3][12];
        {
            const float* r0 = xc + iy0 * Wn + q * 4;
            const float* r1 = xc + iy1 * Wn + q * 4;
            const float* r2 = xc + iy2 * Wn + q * 4;
            float4 a0 = (vy0 & vq0) ? *(const float4*)(r0 - 4) : z4;
            float4 a1 =  vy0        ? *(const float4*)(r0)     : z4;
            float4 a2 = (vy0 & vq2) ? *(const float4*)(r0 + 4) : z4;
            float4 b0 =  vq0        ? *(const float4*)(r1 - 4) : z4;
            float4 b1 =               *(const float4*)(r1);
            float4 b2 =  vq2        ? *(const float4*)(r1 + 4) : z4;
            float4 c0 = (vy2 & vq0) ? *(const float4*)(r2 - 4) : z4;
            float4 c1 =  vy2        ? *(const float4*)(r2)     : z4;
            float4 c2 = (vy2 & vq2) ? *(const float4*)(r2 + 4) : z4;
            sg[0][0]=a0.x; sg[0][1]=a0.y; sg[0][2]=a0.z; sg[0][3]=a0.w;
            sg[0][4]=a1.x; sg[0][5]=a1.y; sg[0][6]=a1.z; sg[0][7]=a1.w;
            sg[0][8]=a2.x; sg[0][9]=a2.y; sg[0][10]=a2.z; sg[0][11]=a2.w;
            sg[1][0]=b0.x; sg[1][1]=b0.y; sg[1][2]=b0.z; sg[1][3]=b0.w;
            sg[1][4]=b1.x; sg[1][5]=b1.y; sg[1][6]=b1.z; sg[1][7]=b1.w;
            sg[1][8]=b2.x; sg[1][9]=b2.y; sg[1][10]=b2.z; sg[1][11]=b2.w;
            sg[2][0]=c0.x; sg[2][1]=c0.y; sg[2][2]=c0.z; sg[2][3]=c0.w;
            sg[2][4]=c1.x; sg[2][5]=c1.y; sg[2][6]=c1.z; sg[2][7]=c1.w;
            sg[2][8]=c2.x; sg[2][9]=c2.y; sg[2][10]=c2.z; sg[2][11]=c2.w;
        }
        const float* wc = wp + c * 28;
        // acc[j][o] over taps in (ky,kx) = k order — same order as R3
#pragma unroll
        for (int o = 0; o < 3; ++o)
#pragma unroll
            for (int ky = 0; ky < 3; ++ky)
#pragma unroll
                for (int kx = 0; kx < 3; ++kx) {
                    float w = wc[o * 9 + ky * 3 + kx];
#pragma unroll
                    for (int j = 0; j < 4; ++j)
                        acc[j][o] = fmaf(sg[ky][j + 2 * kx + 2], w, acc[j][o]);
                }
    }
#pragma unroll
    for (int o = 0; o < 3; ++o) {
        size_t off = (((size_t)b * 54 + tr * 3 + o) * HOn + ho) * WOn + q * 4;
        ushort4 pv = {f2bf(acc[0][o]), f2bf(acc[1][o]), f2bf(acc[2][o]), f2bf(acc[3][o])};
        *(ushort4*)&om[off] = pv;
    }
}

// ---------------------------------------------------------------------------
// Kernel 2: fused deformable gather + bf16 MFMA, M=32 tiles.
// Grid 1024 = 8b x 64ho x 2 pos-halves, XCD swizzle b = id & 7, 4 blocks/CU.
// Gather: dwordx2 corner pairs at xs=clamp(x0,0,62); boundary handled by
// pre-swapped bilinear weights (zero weight lands on the garbage slot).
// B-fragments read directly from global wt (each wave reads its own 4 KB
// quarter-slab, L2-hot) — no s_w.
// LDS: 4608 (val) + 9216 (cw) + 2304 (pk) = 16128 B.
// ---------------------------------------------------------------------------
__global__ __launch_bounds__(256, 4) void dcn_main(const float* __restrict__ x,
                                                   const unsigned short* __restrict__ om,
                                                   const unsigned short* __restrict__ wtp,
                                                   float* __restrict__ out) {
    __shared__ __align__(16) unsigned short s_val[32 * PITCH];   // [pos][c]
    __shared__ float4 s_cw[18][32];
    __shared__ int    s_pk[18][32];

    const int t  = threadIdx.x;
    const int id = blockIdx.x;               // [0, 1024)
    const int b  = id & 7;                   // XCD-aware swizzle
    const int ho = (id >> 3) & 63;
    const int mh = id >> 9;                  // pos half 0/1

    // ---- sampling params for all (gk, pos) of this half-row ----
    for (int e = t; e < 18 * 32; e += 256) {
        int pos = e & 31;
        int wo  = mh * 32 + pos;
        int gk  = e >> 5;
        int g   = gk / 9, k = gk - g * 9;
        int ky  = k / 3,  kx = k - ky * 3;
        const unsigned short* omb = om + (size_t)b * 54 * (HOn * WOn) + ho * WOn + wo;
        float offy = bf2f(omb[(g * 18 + k * 2 + 0) * (HOn * WOn)]);
        float offx = bf2f(omb[(g * 18 + k * 2 + 1) * (HOn * WOn)]);
        float mk   = bf2f(omb[(36 + g * 9 + k) * (HOn * WOn)]);
        mk = 2.0f / (1.0f + __expf(-mk));

        float py = offy + (float)(ky * 2 + ho - 2);
        float px = offx + (float)(kx * 2 + wo - 2);
        float fy = floorf(py), fx = floorf(px);
        int   y0 = (int)fy,    x0 = (int)fx;
        float wy = py - fy,    wx = px - fx;

        bool vy0 = (y0 >= 0) & (y0 < Hn);
        bool vy1 = (y0 + 1 >= 0) & (y0 + 1 < Hn);
        bool vx0 = (x0 >= 0) & (x0 < Wn);
        bool vx1 = (x0 + 1 >= 0) & (x0 + 1 < Wn);
        float4 cw;
        cw.x = (vy0 & vx0) ? (1.f - wy) * (1.f - wx) * mk : 0.f;
        cw.y = (vy0 & vx1) ? (1.f - wy) * wx * mk : 0.f;
        cw.z = (vy1 & vx0) ? wy * (1.f - wx) * mk : 0.f;
        cw.w = (vy1 & vx1) ? wy * wx * mk : 0.f;

        int y0c = min(max(y0, 0), Hn - 1);
        int y1c = min(max(y0 + 1, 0), Hn - 1);
        // paired-load start col; swap weights if corner0 sits in slot .y
        int xs = min(max(x0, 0), Wn - 2);
        if (x0 != xs) {
            float tmp = cw.x; cw.x = cw.y; cw.y = tmp;
            tmp = cw.z; cw.z = cw.w; cw.w = tmp;
        }
        s_cw[gk][pos] = cw;
        s_pk[gk][pos] = y0c | (y1c << 8) | (xs << 16);
    }
    __syncthreads();

    const int lane = t & 63;
    const int wv   = t >> 6;                 // wave id 0..3
    const int lr   = lane & 15;              // MFMA row/col part
    const int lk   = (lane >> 4) * 8;        // MFMA k offset (shorts)
    const int pos  = lane & 31;              // gather: position
    const int oct  = lane >> 5;              // gather: channel octet 0/1
    const int co   = wv * 16 + oct * 8;      // first of this thread's 8 channels

    f32x4 acc[2][2];
#pragma unroll
    for (int mt = 0; mt < 2; ++mt)
#pragma unroll
        for (int nt = 0; nt < 2; ++nt) acc[mt][nt] = (f32x4){0.f, 0.f, 0.f, 0.f};

    for (int gk = 0; gk < 18; ++gk) {
        // ---- B fragments direct from global (L2-hot), issued first ----
        const unsigned short* wrow = wtp + (size_t)gk * 128 * PITCH;
        short8 bfr[2][2];
#pragma unroll
        for (int ks = 0; ks < 2; ++ks)
#pragma unroll
            for (int nt = 0; nt < 2; ++nt)
                bfr[ks][nt] = *(const short8*)&wrow[(wv * 32 + nt * 16 + lr) * PITCH + ks * 32 + lk];

        // ---- gather: 8 channels x 2 rows, paired corners ----
        {
            const int g = gk / 9;
            float4 cw = s_cw[gk][pos];
            int pk  = s_pk[gk][pos];
            int y0r = (pk & 255) * Wn;
            int y1r = ((pk >> 8) & 255) * Wn;
            int xs  = (pk >> 16) & 255;
            const float* xb = x + ((size_t)(b * Cn + g * Cgn + co)) * (Hn * Wn);
            float2 p0[8], p1[8];
#pragma unroll
            for (int i = 0; i < 8; ++i) {
                const float* xc = xb + (size_t)i * (Hn * Wn);
                p0[i] = *(const float2*)(xc + y0r + xs);
                p1[i] = *(const float2*)(xc + y1r + xs);
            }
            short8 hv;
#pragma unroll
            for (int i = 0; i < 8; ++i) {
                float v = cw.x * p0[i].x + cw.y * p0[i].y +
                          cw.z * p1[i].x + cw.w * p1[i].y;
                hv[i] = (short)f2bf(v);
            }
            *(short8*)&s_val[pos * PITCH + co] = hv;
        }
        __syncthreads();

        // ---- 2 K-steps of MFMA over the 64-channel tile ----
#pragma unroll
        for (int ks = 0; ks < 2; ++ks) {
            short8 af[2];
#pragma unroll
            for (int mt = 0; mt < 2; ++mt)
                af[mt] = *(const short8*)&s_val[(mt * 16 + lr) * PITCH + ks * 32 + lk];
#pragma unroll
            for (int mt = 0; mt < 2; ++mt)
#pragma unroll
                for (int nt = 0; nt < 2; ++nt)
                    acc[mt][nt] = __builtin_amdgcn_mfma_f32_16x16x32_bf16(
                        af[mt], bfr[ks][nt], acc[mt][nt], 0, 0, 0);
        }
        __syncthreads();
    }

    // ---- epilogue: D col = oc (lane&15), row = pos ((lane>>4)*4 + reg) ----
#pragma unroll
    for (int mt = 0; mt < 2; ++mt)
#pragma unroll
        for (int nt = 0; nt < 2; ++nt) {
            int oc = wv * 32 + nt * 16 + lr;
            int p0 = mt * 16 + (lane >> 4) * 4;
            float4 v = {acc[mt][nt][0], acc[mt][nt][1], acc[mt][nt][2], acc[mt][nt][3]};
            *(float4*)&out[(((size_t)b * Con + oc) * HOn + ho) * WOn + mh * 32 + p0] = v;
        }
}

// ---------------------------------------------------------------------------
extern "C" void kernel_launch(void* const* d_in, const int* in_sizes, int n_in,
                              void* d_out, int out_size, void* d_ws, size_t ws_size,
                              hipStream_t stream) {
    const float* x  = (const float*)d_in[0];   // [8,128,64,64]
    const float* ow = (const float*)d_in[1];   // [54,64,3,3]
    const float* ob = (const float*)d_in[2];   // [54]
    const float* w  = (const float*)d_in[3];   // [128,128,3,3]
    float* out = (float*)d_out;                // [8,128,64,64]

    // workspace: om bf16 (3538944 B) | wt bf16 (331776 B) | owp f32 (129024 B)
    unsigned short* om = (unsigned short*)d_ws;
    unsigned short* wt = (unsigned short*)((char*)d_ws + 3538944);
    float* owp = (float*)((char*)d_ws + 3538944 + 331776);

    hipLaunchKernelGGL(wt_transpose, dim3(648), dim3(256), 0, stream, w, wt);
    hipLaunchKernelGGL(ow_pack, dim3(126), dim3(256), 0, stream, ow, owp);
    hipLaunchKernelGGL(offset_conv, dim3(576), dim3(256), 0, stream,
                       x, owp, ob, om);
    hipLaunchKernelGGL(dcn_main, dim3(1024), dim3(256), 0, stream,
                       x, om, wt, out);
}

// Round 7
// 125.634 us; speedup vs baseline: 2.8792x; 2.8792x over previous
//
#include <hip/hip_runtime.h>
#include <hip/hip_bf16.h>

// Problem constants
static constexpr int Bn = 8, Cn = 128, Hn = 64, Wn = 64, Con = 128;
static constexpr int KKn = 9, DGn = 2, Cgn = 64;
static constexpr int HOn = 64, WOn = 64;
static constexpr int PITCH = 72;     // bf16 row pitch for s_val

typedef short short8 __attribute__((ext_vector_type(8)));
typedef float f32x4  __attribute__((ext_vector_type(4)));

__device__ __forceinline__ unsigned short f2bf(float f) {
    unsigned u = __float_as_uint(f);
    u += 0x7fff + ((u >> 16) & 1);          // round-to-nearest-even
    return (unsigned short)(u >> 16);
}
__device__ __forceinline__ float bf2f(unsigned short h) {
    return __uint_as_float(((unsigned)h) << 16);
}

// ---------------------------------------------------------------------------
// Kernel A: x NCHW fp32 -> x_t NHWC bf16. Block = (b, y). Phase 1 reads rows
// coalesced into LDS; phase 2 writes 16B-contiguous NHWC chunks.
// ---------------------------------------------------------------------------
__global__ __launch_bounds__(256) void x_cast(const float* __restrict__ x,
                                              unsigned short* __restrict__ xt) {
    __shared__ unsigned short s[128 * 64];       // 16 KB [c][x]
    const int id = blockIdx.x;                   // [0,512)
    const int b = id & 7, y = id >> 3;
    const int t = threadIdx.x;
#pragma unroll
    for (int i = 0; i < 32; ++i) {
        int e = t + i * 256;                     // [0,8192)
        int c = e >> 6, xc = e & 63;
        s[c * 64 + xc] = f2bf(x[(((size_t)b * Cn + c) * Hn + y) * Wn + xc]);
    }
    __syncthreads();
    unsigned short* dst = xt + ((size_t)(b * 64 + y) * 64) * 128;
#pragma unroll
    for (int i = 0; i < 4; ++i) {
        int e = t + i * 256;                     // short8 id [0,1024)
        int xc = e >> 4;
        int c0 = (e & 15) * 8;
        short8 v;
#pragma unroll
        for (int j = 0; j < 8; ++j) v[j] = (short)s[(c0 + j) * 64 + xc];
        *(short8*)&dst[(size_t)e * 8] = v;
    }
}

// ---------------------------------------------------------------------------
// Kernel B: main weight -> MFMA B-fragment order.
// wt2[gk][ks][tile][lane][j] = bf16(w[oc=tile*16+(lane&15)][g*64 + c][k])
// with c = ks*32 + (lane>>4)*8 + j.  18*2*8*64*8 = 147456 elems, grid 576.
// ---------------------------------------------------------------------------
__global__ __launch_bounds__(256) void wt_frag(const float* __restrict__ w,
                                               unsigned short* __restrict__ wt2) {
    int e    = blockIdx.x * 256 + threadIdx.x;   // [0,147456)
    int j    = e & 7;
    int lane = (e >> 3) & 63;
    int tile = (e >> 9) & 7;
    int ks   = (e >> 12) & 1;
    int gk   = e >> 13;                          // 0..17
    int g = gk / 9, k = gk - g * 9;
    int oc = tile * 16 + (lane & 15);
    int c  = ks * 32 + (lane >> 4) * 8 + j;
    wt2[e] = f2bf(w[((size_t)oc * Cn + g * Cgn + c) * KKn + k]);
}

// ---------------------------------------------------------------------------
// Kernel C: offset weights -> MFMA B-fragment order.
// owf[g][ks][nt][lane][j]: ks in [0,18) = tap*2 + chalf;
// value = ow[g*27 + nt*16+(lane&15)][chalf*32+(lane>>4)*8+j][tap] (0 if oc>=27)
// 2*18*2*64*8 = 36864 elems, grid 144.
// ---------------------------------------------------------------------------
__global__ __launch_bounds__(256) void ow_frag(const float* __restrict__ ow,
                                               unsigned short* __restrict__ owf) {
    int e = blockIdx.x * 256 + threadIdx.x;      // [0,36864)
    int g  = e / 18432;
    int r  = e - g * 18432;
    int ks = r >> 10;                            // /1024
    int r2 = r & 1023;
    int nt = r2 >> 9;
    int lane = (r2 >> 3) & 63;
    int j  = r2 & 7;
    int tap = ks >> 1, chalf = ks & 1;
    int oc_l = nt * 16 + (lane & 15);
    int c = chalf * 32 + (lane >> 4) * 8 + j;
    float v = 0.f;
    if (oc_l < 27)
        v = ow[((size_t)(g * 27 + oc_l) * Cgn + c) * KKn + tap];
    owf[e] = f2bf(v);
}

// ---------------------------------------------------------------------------
// Kernel 1: offset conv as MFMA GEMM. Block = (b, ho, g), grid 1024, XCD
// swizzle b = id & 7. A-fragments read DIRECTLY from global x_t (16B
// contiguous per lane); B-fragments from owf (lane-contiguous). M=64 wo
// (wave = one 16-row m-tile), N=32 (27 used), K=576 (tap-uniform K-steps;
// invalid-y taps skipped = zero padding; invalid-x lanes cndmask-zeroed).
// ---------------------------------------------------------------------------
__global__ __launch_bounds__(256) void offset_conv(const unsigned short* __restrict__ xt,
                                                   const unsigned short* __restrict__ owf,
                                                   const float* __restrict__ ob,
                                                   unsigned short* __restrict__ om) {
    const int id = blockIdx.x;                   // [0,1024)
    const int b  = id & 7;
    const int ho = (id >> 3) & 63;
    const int g  = id >> 9;
    const int t  = threadIdx.x;
    const int lane = t & 63;
    const int wv = t >> 6;
    const int lr = lane & 15;
    const int lk8 = (lane >> 4) * 8;
    const int wo = wv * 16 + lr;                 // A-row this lane feeds

    f32x4 acc[2];
#pragma unroll
    for (int nt = 0; nt < 2; ++nt) {
        int oc_l = nt * 16 + lr;
        float bias = (oc_l < 27) ? ob[g * 27 + oc_l] : 0.f;
        acc[nt] = (f32x4){bias, bias, bias, bias};
    }

    const unsigned short* xb = xt + (size_t)b * (Hn * Wn * Cn) + g * Cgn;
    const unsigned short* wf = owf + (size_t)g * 18432;
    const short8 zz = {0, 0, 0, 0, 0, 0, 0, 0};

    for (int tap = 0; tap < 9; ++tap) {
        int ky = tap / 3, kx = tap - ky * 3;
        int y = ho - 2 + 2 * ky;
        if (y < 0 || y >= Hn) continue;          // wave-uniform skip (zero pad)
        int xc = wo - 2 + 2 * kx;
        bool vx = (xc >= 0) & (xc < Wn);
        int xcc = min(max(xc, 0), Wn - 1);
        const unsigned short* arow = xb + ((size_t)y * Wn + xcc) * Cn;
#pragma unroll
        for (int ch = 0; ch < 2; ++ch) {
            int ks = tap * 2 + ch;
            short8 av = *(const short8*)&arow[ch * 32 + lk8];
            av = vx ? av : zz;
            const unsigned short* bb = wf + (size_t)ks * 1024 + lane * 8;
            short8 bv0 = *(const short8*)&bb[0];
            short8 bv1 = *(const short8*)&bb[512];
            acc[0] = __builtin_amdgcn_mfma_f32_16x16x32_bf16(av, bv0, acc[0], 0, 0, 0);
            acc[1] = __builtin_amdgcn_mfma_f32_16x16x32_bf16(av, bv1, acc[1], 0, 0, 0);
        }
    }

    // D: row = wo-part ((lane>>4)*4+reg), col = oc_l (lane&15 + nt*16)
    const int q = lane >> 4;
#pragma unroll
    for (int nt = 0; nt < 2; ++nt) {
        int oc_l = nt * 16 + lr;
        if (oc_l < 27) {
            size_t base = (((size_t)b * 54 + g * 27 + oc_l) * HOn + ho) * WOn + wv * 16 + q * 4;
#pragma unroll
            for (int r = 0; r < 4; ++r) om[base + r] = f2bf(acc[nt][r]);
        }
    }
}

// ---------------------------------------------------------------------------
// Kernel 2: fused deformable gather + bf16 MFMA. Grid 512 = (b = id&7 XCD
// swizzle, ho). Gather from NHWC x_t: thread = (pos = t>>2, 16-ch chunk),
// 8 coalesced dwordx4 corner loads per gk. B-fragments lane-contiguous from
// wt2. Param phase + MFMA + epilogue = R5-proven.
// LDS: 9216 (s_val) + 18432 (s_cw) + 4608 (s_pk) = 32256 B.
// ---------------------------------------------------------------------------
__global__ __launch_bounds__(256, 2) void dcn_main(const unsigned short* __restrict__ xt,
                                                   const unsigned short* __restrict__ om,
                                                   const unsigned short* __restrict__ wt2,
                                                   float* __restrict__ out) {
    __shared__ __align__(16) unsigned short s_val[64 * PITCH];   // [pos][c]
    __shared__ float4 s_cw[18][64];
    __shared__ int    s_pk[18][64];

    const int t  = threadIdx.x;
    const int id = blockIdx.x;               // [0, 512)
    const int b  = id & 7;                   // XCD-aware swizzle
    const int ho = id >> 3;

    // ---- sampling params for all (g,k,wo) of this row (R5-proven) ----
    for (int e = t; e < 18 * 64; e += 256) {
        int wo = e & 63;
        int gk = e >> 6;
        int g  = gk / 9, k = gk - g * 9;
        int ky = k / 3,  kx = k - ky * 3;
        const unsigned short* omb = om + (size_t)b * 54 * (HOn * WOn) + ho * WOn + wo;
        float offy = bf2f(omb[(g * 18 + k * 2 + 0) * (HOn * WOn)]);
        float offx = bf2f(omb[(g * 18 + k * 2 + 1) * (HOn * WOn)]);
        float mk   = bf2f(omb[(36 + g * 9 + k) * (HOn * WOn)]);
        mk = 2.0f / (1.0f + __expf(-mk));

        float py = offy + (float)(ky * 2 + ho - 2);
        float px = offx + (float)(kx * 2 + wo - 2);
        float fy = floorf(py), fx = floorf(px);
        int   y0 = (int)fy,    x0 = (int)fx;
        float wy = py - fy,    wx = px - fx;

        bool vy0 = (y0 >= 0) & (y0 < Hn);
        bool vy1 = (y0 + 1 >= 0) & (y0 + 1 < Hn);
        bool vx0 = (x0 >= 0) & (x0 < Wn);
        bool vx1 = (x0 + 1 >= 0) & (x0 + 1 < Wn);
        float4 cw;
        cw.x = (vy0 & vx0) ? (1.f - wy) * (1.f - wx) * mk : 0.f;
        cw.y = (vy0 & vx1) ? (1.f - wy) * wx * mk : 0.f;
        cw.z = (vy1 & vx0) ? wy * (1.f - wx) * mk : 0.f;
        cw.w = (vy1 & vx1) ? wy * wx * mk : 0.f;

        int y0c = min(max(y0, 0), Hn - 1);
        int y1c = min(max(y0 + 1, 0), Hn - 1);
        int x0c = min(max(x0, 0), Wn - 1);
        int x1c = min(max(x0 + 1, 0), Wn - 1);
        s_cw[gk][wo] = cw;
        s_pk[gk][wo] = y0c | (y1c << 8) | (x0c << 16) | (x1c << 24);
    }
    __syncthreads();

    const int lane = t & 63;
    const int wv   = t >> 6;                 // wave id 0..3
    const int lr   = lane & 15;              // MFMA row/col part
    const int lk   = (lane >> 4) * 8;        // MFMA k offset (shorts)
    const int pos  = t >> 2;                 // gather: position 0..63
    const int cq   = (t & 3) * 16;           // gather: 16-ch chunk (group-local)

    f32x4 acc[4][2];
#pragma unroll
    for (int mt = 0; mt < 4; ++mt)
#pragma unroll
        for (int nt = 0; nt < 2; ++nt) acc[mt][nt] = (f32x4){0.f, 0.f, 0.f, 0.f};

    const unsigned short* xb0 = xt + (size_t)b * (Hn * Wn * Cn);

    for (int gk = 0; gk < 18; ++gk) {
        // ---- B fragments, lane-contiguous from wt2 (L2-hot) ----
        const unsigned short* wf = wt2 + (size_t)gk * 8192;
        short8 bfr[2][2];
#pragma unroll
        for (int ks = 0; ks < 2; ++ks)
#pragma unroll
            for (int nt = 0; nt < 2; ++nt)
                bfr[ks][nt] = *(const short8*)&wf[(size_t)(ks * 8 + wv * 2 + nt) * 512 + lane * 8];

        // ---- gather: 4 corners x 16 channels, coalesced NHWC loads ----
        {
            const int g = gk / 9;
            float4 cw = s_cw[gk][pos];
            int pk  = s_pk[gk][pos];
            int y0c = pk & 255, y1c = (pk >> 8) & 255;
            int x0c = (pk >> 16) & 255, x1c = (pk >> 24) & 255;
            const unsigned short* xb = xb0 + g * Cgn + cq;
            const unsigned short* p00 = xb + ((size_t)y0c * Wn + x0c) * Cn;
            const unsigned short* p01 = xb + ((size_t)y0c * Wn + x1c) * Cn;
            const unsigned short* p10 = xb + ((size_t)y1c * Wn + x0c) * Cn;
            const unsigned short* p11 = xb + ((size_t)y1c * Wn + x1c) * Cn;
            short8 a00 = *(const short8*)&p00[0], b00 = *(const short8*)&p00[8];
            short8 a01 = *(const short8*)&p01[0], b01 = *(const short8*)&p01[8];
            short8 a10 = *(const short8*)&p10[0], b10 = *(const short8*)&p10[8];
            short8 a11 = *(const short8*)&p11[0], b11 = *(const short8*)&p11[8];
            short8 h0, h1;
#pragma unroll
            for (int i = 0; i < 8; ++i) {
                float v = cw.x * bf2f((unsigned short)a00[i]) +
                          cw.y * bf2f((unsigned short)a01[i]) +
                          cw.z * bf2f((unsigned short)a10[i]) +
                          cw.w * bf2f((unsigned short)a11[i]);
                h0[i] = (short)f2bf(v);
            }
#pragma unroll
            for (int i = 0; i < 8; ++i) {
                float v = cw.x * bf2f((unsigned short)b00[i]) +
                          cw.y * bf2f((unsigned short)b01[i]) +
                          cw.z * bf2f((unsigned short)b10[i]) +
                          cw.w * bf2f((unsigned short)b11[i]);
                h1[i] = (short)f2bf(v);
            }
            *(short8*)&s_val[pos * PITCH + cq]     = h0;
            *(short8*)&s_val[pos * PITCH + cq + 8] = h1;
        }
        __syncthreads();

        // ---- 2 K-steps of MFMA (R5-proven) ----
#pragma unroll
        for (int ks = 0; ks < 2; ++ks) {
            short8 af[4];
#pragma unroll
            for (int mt = 0; mt < 4; ++mt)
                af[mt] = *(const short8*)&s_val[(mt * 16 + lr) * PITCH + ks * 32 + lk];
#pragma unroll
            for (int mt = 0; mt < 4; ++mt)
#pragma unroll
                for (int nt = 0; nt < 2; ++nt)
                    acc[mt][nt] = __builtin_amdgcn_mfma_f32_16x16x32_bf16(
                        af[mt], bfr[ks][nt], acc[mt][nt], 0, 0, 0);
        }
        __syncthreads();
    }

    // ---- epilogue (R5-proven): D col = oc, row = pos ----
#pragma unroll
    for (int mt = 0; mt < 4; ++mt)
#pragma unroll
        for (int nt = 0; nt < 2; ++nt) {
            int oc = wv * 32 + nt * 16 + lr;
            int p0 = mt * 16 + (lane >> 4) * 4;
            float4 v = {acc[mt][nt][0], acc[mt][nt][1], acc[mt][nt][2], acc[mt][nt][3]};
            *(float4*)&out[(((size_t)b * Con + oc) * HOn + ho) * WOn + p0] = v;
        }
}

// ---------------------------------------------------------------------------
extern "C" void kernel_launch(void* const* d_in, const int* in_sizes, int n_in,
                              void* d_out, int out_size, void* d_ws, size_t ws_size,
                              hipStream_t stream) {
    const float* x  = (const float*)d_in[0];   // [8,128,64,64]
    const float* ow = (const float*)d_in[1];   // [54,64,3,3]
    const float* ob = (const float*)d_in[2];   // [54]
    const float* w  = (const float*)d_in[3];   // [128,128,3,3]
    float* out = (float*)d_out;                // [8,128,64,64]

    // ws: om bf16 3,538,944 | x_t bf16 8,388,608 | wt2 294,912 | owf 73,728
    unsigned short* om  = (unsigned short*)d_ws;
    unsigned short* xt  = (unsigned short*)((char*)d_ws + 3538944);
    unsigned short* wt2 = (unsigned short*)((char*)d_ws + 3538944 + 8388608);
    unsigned short* owf = (unsigned short*)((char*)d_ws + 3538944 + 8388608 + 294912);

    hipLaunchKernelGGL(x_cast,  dim3(512), dim3(256), 0, stream, x, xt);
    hipLaunchKernelGGL(wt_frag, dim3(576), dim3(256), 0, stream, w, wt2);
    hipLaunchKernelGGL(ow_frag, dim3(144), dim3(256), 0, stream, ow, owf);
    hipLaunchKernelGGL(offset_conv, dim3(1024), dim3(256), 0, stream,
                       xt, owf, ob, om);
    hipLaunchKernelGGL(dcn_main, dim3(512), dim3(256), 0, stream,
                       xt, om, wt2, out);
}

// Round 8
// 121.054 us; speedup vs baseline: 2.9881x; 1.0378x over previous
//
#include <hip/hip_runtime.h>
#include <hip/hip_bf16.h>

// Problem constants
static constexpr int Bn = 8, Cn = 128, Hn = 64, Wn = 64, Con = 128;
static constexpr int KKn = 9, DGn = 2, Cgn = 64;
static constexpr int HOn = 64, WOn = 64;
static constexpr int PITCH = 72;     // bf16 row pitch for s_val

typedef short short8 __attribute__((ext_vector_type(8)));
typedef float f32x4  __attribute__((ext_vector_type(4)));

__device__ __forceinline__ unsigned short f2bf(float f) {
    unsigned u = __float_as_uint(f);
    u += 0x7fff + ((u >> 16) & 1);          // round-to-nearest-even
    return (unsigned short)(u >> 16);
}
__device__ __forceinline__ float bf2f(unsigned short h) {
    return __uint_as_float(((unsigned)h) << 16);
}

// ---------------------------------------------------------------------------
// Kernel A: x NCHW fp32 -> x_t NHWC bf16. Block = (b, y). Phase 1 reads rows
// coalesced into LDS; phase 2 writes 16B-contiguous NHWC chunks.
// ---------------------------------------------------------------------------
__global__ __launch_bounds__(256) void x_cast(const float* __restrict__ x,
                                              unsigned short* __restrict__ xt) {
    __shared__ unsigned short s[128 * 64];       // 16 KB [c][x]
    const int id = blockIdx.x;                   // [0,512)
    const int b = id & 7, y = id >> 3;
    const int t = threadIdx.x;
#pragma unroll
    for (int i = 0; i < 32; ++i) {
        int e = t + i * 256;                     // [0,8192)
        int c = e >> 6, xc = e & 63;
        s[c * 64 + xc] = f2bf(x[(((size_t)b * Cn + c) * Hn + y) * Wn + xc]);
    }
    __syncthreads();
    unsigned short* dst = xt + ((size_t)(b * 64 + y) * 64) * 128;
#pragma unroll
    for (int i = 0; i < 4; ++i) {
        int e = t + i * 256;                     // short8 id [0,1024)
        int xc = e >> 4;
        int c0 = (e & 15) * 8;
        short8 v;
#pragma unroll
        for (int j = 0; j < 8; ++j) v[j] = (short)s[(c0 + j) * 64 + xc];
        *(short8*)&dst[(size_t)e * 8] = v;
    }
}

// ---------------------------------------------------------------------------
// Kernel B: merged weight prep.
// Blocks [0,576): main weight -> MFMA B-fragment order wt2[gk][ks][tile][lane][8].
// Blocks [576,720): offset weights -> owf[g][ks=tap*2+chalf][nt][lane][8].
// ---------------------------------------------------------------------------
__global__ __launch_bounds__(256) void w_prep(const float* __restrict__ w,
                                              const float* __restrict__ ow,
                                              unsigned short* __restrict__ wt2,
                                              unsigned short* __restrict__ owf) {
    const int blk = blockIdx.x;
    const int t = threadIdx.x;
    if (blk < 576) {
        int e    = blk * 256 + t;                // [0,147456)
        int j    = e & 7;
        int lane = (e >> 3) & 63;
        int tile = (e >> 9) & 7;
        int ks   = (e >> 12) & 1;
        int gk   = e >> 13;                      // 0..17
        int g = gk / 9, k = gk - g * 9;
        int oc = tile * 16 + (lane & 15);
        int c  = ks * 32 + (lane >> 4) * 8 + j;
        wt2[e] = f2bf(w[((size_t)oc * Cn + g * Cgn + c) * KKn + k]);
    } else {
        int e = (blk - 576) * 256 + t;           // [0,36864)
        int g  = e / 18432;
        int r  = e - g * 18432;
        int ks = r >> 10;
        int r2 = r & 1023;
        int nt = r2 >> 9;
        int lane = (r2 >> 3) & 63;
        int j  = r2 & 7;
        int tap = ks >> 1, chalf = ks & 1;
        int oc_l = nt * 16 + (lane & 15);
        int c = chalf * 32 + (lane >> 4) * 8 + j;
        float v = 0.f;
        if (oc_l < 27)
            v = ow[((size_t)(g * 27 + oc_l) * Cgn + c) * KKn + tap];
        owf[e] = f2bf(v);
    }
}

// ---------------------------------------------------------------------------
// Kernel 1: offset conv as MFMA GEMM (R7-proven). Block = (b, ho, g),
// grid 1024, XCD swizzle b = id & 7. A-fragments direct from global x_t,
// B-fragments lane-contiguous from owf. M=64, N=32 (27 used), K=576.
// ---------------------------------------------------------------------------
__global__ __launch_bounds__(256) void offset_conv(const unsigned short* __restrict__ xt,
                                                   const unsigned short* __restrict__ owf,
                                                   const float* __restrict__ ob,
                                                   unsigned short* __restrict__ om) {
    const int id = blockIdx.x;                   // [0,1024)
    const int b  = id & 7;
    const int ho = (id >> 3) & 63;
    const int g  = id >> 9;
    const int t  = threadIdx.x;
    const int lane = t & 63;
    const int wv = t >> 6;
    const int lr = lane & 15;
    const int lk8 = (lane >> 4) * 8;
    const int wo = wv * 16 + lr;                 // A-row this lane feeds

    f32x4 acc[2];
#pragma unroll
    for (int nt = 0; nt < 2; ++nt) {
        int oc_l = nt * 16 + lr;
        float bias = (oc_l < 27) ? ob[g * 27 + oc_l] : 0.f;
        acc[nt] = (f32x4){bias, bias, bias, bias};
    }

    const unsigned short* xb = xt + (size_t)b * (Hn * Wn * Cn) + g * Cgn;
    const unsigned short* wf = owf + (size_t)g * 18432;
    const short8 zz = {0, 0, 0, 0, 0, 0, 0, 0};

    for (int tap = 0; tap < 9; ++tap) {
        int ky = tap / 3, kx = tap - ky * 3;
        int y = ho - 2 + 2 * ky;
        if (y < 0 || y >= Hn) continue;          // wave-uniform skip (zero pad)
        int xc = wo - 2 + 2 * kx;
        bool vx = (xc >= 0) & (xc < Wn);
        int xcc = min(max(xc, 0), Wn - 1);
        const unsigned short* arow = xb + ((size_t)y * Wn + xcc) * Cn;
#pragma unroll
        for (int ch = 0; ch < 2; ++ch) {
            int ks = tap * 2 + ch;
            short8 av = *(const short8*)&arow[ch * 32 + lk8];
            av = vx ? av : zz;
            const unsigned short* bb = wf + (size_t)ks * 1024 + lane * 8;
            short8 bv0 = *(const short8*)&bb[0];
            short8 bv1 = *(const short8*)&bb[512];
            acc[0] = __builtin_amdgcn_mfma_f32_16x16x32_bf16(av, bv0, acc[0], 0, 0, 0);
            acc[1] = __builtin_amdgcn_mfma_f32_16x16x32_bf16(av, bv1, acc[1], 0, 0, 0);
        }
    }

    // D: row = wo-part ((lane>>4)*4+reg), col = oc_l (lane&15 + nt*16)
    const int q = lane >> 4;
#pragma unroll
    for (int nt = 0; nt < 2; ++nt) {
        int oc_l = nt * 16 + lr;
        if (oc_l < 27) {
            size_t base = (((size_t)b * 54 + g * 27 + oc_l) * HOn + ho) * WOn + wv * 16 + q * 4;
#pragma unroll
            for (int r = 0; r < 4; ++r) om[base + r] = f2bf(acc[nt][r]);
        }
    }
}

// ---------------------------------------------------------------------------
// Kernel 2: fused deformable gather + bf16 MFMA, M-split for TLP.
// Grid 1024 = (b = id&7 XCD swizzle, ho = (id>>3)&63, mh = id>>9: 32-pos half).
// 4 blocks/CU (launch_bounds(256,4)), LDS 16.1 KB. Gather from NHWC x_t:
// thread = (pos = t>>3 in [0,32), 8-ch chunk (t&7)*8); 4 coalesced 16B corner
// loads per thread. B-fragments lane-contiguous from wt2 (L2-hot).
// Numerics bit-identical to R7 (same per-output FMA/MFMA order).
// LDS: 4608 (s_val) + 9216 (s_cw) + 2304 (s_pk) = 16128 B.
// ---------------------------------------------------------------------------
__global__ __launch_bounds__(256, 4) void dcn_main(const unsigned short* __restrict__ xt,
                                                   const unsigned short* __restrict__ om,
                                                   const unsigned short* __restrict__ wt2,
                                                   float* __restrict__ out) {
    __shared__ __align__(16) unsigned short s_val[32 * PITCH];   // [pos][c]
    __shared__ float4 s_cw[18][32];
    __shared__ int    s_pk[18][32];

    const int t  = threadIdx.x;
    const int id = blockIdx.x;               // [0, 1024)
    const int b  = id & 7;                   // XCD-aware swizzle
    const int ho = (id >> 3) & 63;
    const int mh = id >> 9;                  // pos half 0/1

    // ---- sampling params for all (gk, pos) of this half-row ----
    for (int e = t; e < 18 * 32; e += 256) {
        int pos = e & 31;
        int wo  = mh * 32 + pos;
        int gk  = e >> 5;
        int g  = gk / 9, k = gk - g * 9;
        int ky = k / 3,  kx = k - ky * 3;
        const unsigned short* omb = om + (size_t)b * 54 * (HOn * WOn) + ho * WOn + wo;
        float offy = bf2f(omb[(g * 18 + k * 2 + 0) * (HOn * WOn)]);
        float offx = bf2f(omb[(g * 18 + k * 2 + 1) * (HOn * WOn)]);
        float mk   = bf2f(omb[(36 + g * 9 + k) * (HOn * WOn)]);
        mk = 2.0f / (1.0f + __expf(-mk));

        float py = offy + (float)(ky * 2 + ho - 2);
        float px = offx + (float)(kx * 2 + wo - 2);
        float fy = floorf(py), fx = floorf(px);
        int   y0 = (int)fy,    x0 = (int)fx;
        float wy = py - fy,    wx = px - fx;

        bool vy0 = (y0 >= 0) & (y0 < Hn);
        bool vy1 = (y0 + 1 >= 0) & (y0 + 1 < Hn);
        bool vx0 = (x0 >= 0) & (x0 < Wn);
        bool vx1 = (x0 + 1 >= 0) & (x0 + 1 < Wn);
        float4 cw;
        cw.x = (vy0 & vx0) ? (1.f - wy) * (1.f - wx) * mk : 0.f;
        cw.y = (vy0 & vx1) ? (1.f - wy) * wx * mk : 0.f;
        cw.z = (vy1 & vx0) ? wy * (1.f - wx) * mk : 0.f;
        cw.w = (vy1 & vx1) ? wy * wx * mk : 0.f;

        int y0c = min(max(y0, 0), Hn - 1);
        int y1c = min(max(y0 + 1, 0), Hn - 1);
        int x0c = min(max(x0, 0), Wn - 1);
        int x1c = min(max(x0 + 1, 0), Wn - 1);
        s_cw[gk][pos] = cw;
        s_pk[gk][pos] = y0c | (y1c << 8) | (x0c << 16) | (x1c << 24);
    }
    __syncthreads();

    const int lane = t & 63;
    const int wv   = t >> 6;                 // wave id 0..3
    const int lr   = lane & 15;              // MFMA row/col part
    const int lk   = (lane >> 4) * 8;        // MFMA k offset (shorts)
    const int pos  = t >> 3;                 // gather: position 0..31
    const int cq   = (t & 7) * 8;            // gather: 8-ch chunk (group-local)

    f32x4 acc[2][2];
#pragma unroll
    for (int mt = 0; mt < 2; ++mt)
#pragma unroll
        for (int nt = 0; nt < 2; ++nt) acc[mt][nt] = (f32x4){0.f, 0.f, 0.f, 0.f};

    const unsigned short* xb0 = xt + (size_t)b * (Hn * Wn * Cn);

    for (int gk = 0; gk < 18; ++gk) {
        // ---- B fragments, lane-contiguous from wt2 (L2-hot) ----
        const unsigned short* wf = wt2 + (size_t)gk * 8192;
        short8 bfr[2][2];
#pragma unroll
        for (int ks = 0; ks < 2; ++ks)
#pragma unroll
            for (int nt = 0; nt < 2; ++nt)
                bfr[ks][nt] = *(const short8*)&wf[(size_t)(ks * 8 + wv * 2 + nt) * 512 + lane * 8];

        // ---- gather: 4 corners x 8 channels, coalesced NHWC loads ----
        {
            const int g = gk / 9;
            float4 cw = s_cw[gk][pos];
            int pk  = s_pk[gk][pos];
            int y0c = pk & 255, y1c = (pk >> 8) & 255;
            int x0c = (pk >> 16) & 255, x1c = (pk >> 24) & 255;
            const unsigned short* xb = xb0 + g * Cgn + cq;
            short8 a00 = *(const short8*)&xb[((size_t)y0c * Wn + x0c) * Cn];
            short8 a01 = *(const short8*)&xb[((size_t)y0c * Wn + x1c) * Cn];
            short8 a10 = *(const short8*)&xb[((size_t)y1c * Wn + x0c) * Cn];
            short8 a11 = *(const short8*)&xb[((size_t)y1c * Wn + x1c) * Cn];
            short8 h0;
#pragma unroll
            for (int i = 0; i < 8; ++i) {
                float v = cw.x * bf2f((unsigned short)a00[i]) +
                          cw.y * bf2f((unsigned short)a01[i]) +
                          cw.z * bf2f((unsigned short)a10[i]) +
                          cw.w * bf2f((unsigned short)a11[i]);
                h0[i] = (short)f2bf(v);
            }
            *(short8*)&s_val[pos * PITCH + cq] = h0;
        }
        __syncthreads();

        // ---- 2 K-steps of MFMA ----
#pragma unroll
        for (int ks = 0; ks < 2; ++ks) {
            short8 af[2];
#pragma unroll
            for (int mt = 0; mt < 2; ++mt)
                af[mt] = *(const short8*)&s_val[(mt * 16 + lr) * PITCH + ks * 32 + lk];
#pragma unroll
            for (int mt = 0; mt < 2; ++mt)
#pragma unroll
                for (int nt = 0; nt < 2; ++nt)
                    acc[mt][nt] = __builtin_amdgcn_mfma_f32_16x16x32_bf16(
                        af[mt], bfr[ks][nt], acc[mt][nt], 0, 0, 0);
        }
        __syncthreads();
    }

    // ---- epilogue: D col = oc, row = pos (within this 32-pos half) ----
#pragma unroll
    for (int mt = 0; mt < 2; ++mt)
#pragma unroll
        for (int nt = 0; nt < 2; ++nt) {
            int oc = wv * 32 + nt * 16 + lr;
            int p0 = mh * 32 + mt * 16 + (lane >> 4) * 4;
            float4 v = {acc[mt][nt][0], acc[mt][nt][1], acc[mt][nt][2], acc[mt][nt][3]};
            *(float4*)&out[(((size_t)b * Con + oc) * HOn + ho) * WOn + p0] = v;
        }
}

// ---------------------------------------------------------------------------
extern "C" void kernel_launch(void* const* d_in, const int* in_sizes, int n_in,
                              void* d_out, int out_size, void* d_ws, size_t ws_size,
                              hipStream_t stream) {
    const float* x  = (const float*)d_in[0];   // [8,128,64,64]
    const float* ow = (const float*)d_in[1];   // [54,64,3,3]
    const float* ob = (const float*)d_in[2];   // [54]
    const float* w  = (const float*)d_in[3];   // [128,128,3,3]
    float* out = (float*)d_out;                // [8,128,64,64]

    // ws: om bf16 3,538,944 | x_t bf16 8,388,608 | wt2 294,912 | owf 73,728
    unsigned short* om  = (unsigned short*)d_ws;
    unsigned short* xt  = (unsigned short*)((char*)d_ws + 3538944);
    unsigned short* wt2 = (unsigned short*)((char*)d_ws + 3538944 + 8388608);
    unsigned short* owf = (unsigned short*)((char*)d_ws + 3538944 + 8388608 + 294912);

    hipLaunchKernelGGL(x_cast, dim3(512), dim3(256), 0, stream, x, xt);
    hipLaunchKernelGGL(w_prep, dim3(720), dim3(256), 0, stream, w, ow, wt2, owf);
    hipLaunchKernelGGL(offset_conv, dim3(1024), dim3(256), 0, stream,
                       xt, owf, ob, om);
    hipLaunchKernelGGL(dcn_main, dim3(1024), dim3(256), 0, stream,
                       xt, om, wt2, out);
}

// Round 9
// 119.778 us; speedup vs baseline: 3.0199x; 1.0107x over previous
//
#include <hip/hip_runtime.h>
#include <hip/hip_bf16.h>

// Problem constants
static constexpr int Bn = 8, Cn = 128, Hn = 64, Wn = 64, Con = 128;
static constexpr int KKn = 9, DGn = 2, Cgn = 64;
static constexpr int HOn = 64, WOn = 64;
static constexpr int PITCH = 72;     // bf16 row pitch for s_val
static constexpr int OMP = 34;       // s_om row pitch (shorts)

typedef short short8 __attribute__((ext_vector_type(8)));
typedef float f32x4  __attribute__((ext_vector_type(4)));

__device__ __forceinline__ unsigned short f2bf(float f) {
    unsigned u = __float_as_uint(f);
    u += 0x7fff + ((u >> 16) & 1);          // round-to-nearest-even
    return (unsigned short)(u >> 16);
}
__device__ __forceinline__ float bf2f(unsigned short h) {
    return __uint_as_float(((unsigned)h) << 16);
}

// ---------------------------------------------------------------------------
// Kernel P: merged prep.
// Blocks [0,512):    x NCHW fp32 -> x_t NHWC bf16 (LDS transpose, b = blk&7).
// Blocks [512,1088): main weight -> MFMA B-frag order wt2[gk][ks][tile][lane][8].
// Blocks [1088,1232): offset weight -> owf[g][ks=tap*2+ch][nt][lane][8].
// ---------------------------------------------------------------------------
__global__ __launch_bounds__(256) void prep(const float* __restrict__ x,
                                            const float* __restrict__ w,
                                            const float* __restrict__ ow,
                                            unsigned short* __restrict__ xt,
                                            unsigned short* __restrict__ wt2,
                                            unsigned short* __restrict__ owf) {
    __shared__ unsigned short s[128 * 64];       // 16 KB [c][x]
    const int blk = blockIdx.x;
    const int t = threadIdx.x;
    if (blk < 512) {
        const int b = blk & 7, y = blk >> 3;
#pragma unroll
        for (int i = 0; i < 32; ++i) {
            int e = t + i * 256;                 // [0,8192)
            int c = e >> 6, xc = e & 63;
            s[c * 64 + xc] = f2bf(x[(((size_t)b * Cn + c) * Hn + y) * Wn + xc]);
        }
        __syncthreads();
        unsigned short* dst = xt + ((size_t)(b * 64 + y) * 64) * 128;
#pragma unroll
        for (int i = 0; i < 4; ++i) {
            int e = t + i * 256;                 // short8 id [0,1024)
            int xc = e >> 4;
            int c0 = (e & 15) * 8;
            short8 v;
#pragma unroll
            for (int j = 0; j < 8; ++j) v[j] = (short)s[(c0 + j) * 64 + xc];
            *(short8*)&dst[(size_t)e * 8] = v;
        }
    } else if (blk < 1088) {
        int e    = (blk - 512) * 256 + t;        // [0,147456)
        int j    = e & 7;
        int lane = (e >> 3) & 63;
        int tile = (e >> 9) & 7;
        int ks   = (e >> 12) & 1;
        int gk   = e >> 13;                      // 0..17
        int g = gk / 9, k = gk - g * 9;
        int oc = tile * 16 + (lane & 15);
        int c  = ks * 32 + (lane >> 4) * 8 + j;
        wt2[e] = f2bf(w[((size_t)oc * Cn + g * Cgn + c) * KKn + k]);
    } else {
        int e = (blk - 1088) * 256 + t;          // [0,36864)
        int g  = e / 18432;
        int r  = e - g * 18432;
        int ks = r >> 10;
        int r2 = r & 1023;
        int nt = r2 >> 9;
        int lane = (r2 >> 3) & 63;
        int j  = r2 & 7;
        int tap = ks >> 1, chalf = ks & 1;
        int oc_l = nt * 16 + (lane & 15);
        int c = chalf * 32 + (lane >> 4) * 8 + j;
        float v = 0.f;
        if (oc_l < 27)
            v = ow[((size_t)(g * 27 + oc_l) * Cgn + c) * KKn + tap];
        owf[e] = f2bf(v);
    }
}

// ---------------------------------------------------------------------------
// Kernel 2: FULLY FUSED offset-conv + deformable gather + bf16 MFMA.
// Grid 1024 = (b = id&7 XCD swizzle, ho = (id>>3)&63, mh = id>>9), 4 blk/CU.
// P0: om row computed in-block via MFMA GEMM (wave = (conv-group cg, n-tile
//     nh); M=32 local wo, K=576, same (tap,ch) order as R7's offset_conv ->
//     bit-identical), f2bf'd into s_om (stride-34 LDS).
// P1: sampling params from s_om (bf2f) — values identical to R8.
// P2: 18-gk gather + MFMA loop (R8-proven, unchanged).
// LDS: 4608 (s_val) + 9216 (s_cw) + 2304 (s_pk) + 3672 (s_om) = 19800 B.
// ---------------------------------------------------------------------------
__global__ __launch_bounds__(256, 4) void dcn_fused(const unsigned short* __restrict__ xt,
                                                    const unsigned short* __restrict__ owf,
                                                    const float* __restrict__ ob,
                                                    const unsigned short* __restrict__ wt2,
                                                    float* __restrict__ out) {
    __shared__ __align__(16) unsigned short s_val[32 * PITCH];   // [pos][c]
    __shared__ float4 s_cw[18][32];
    __shared__ int    s_pk[18][32];
    __shared__ unsigned short s_om[54 * OMP];                    // [c54][pos]

    const int t  = threadIdx.x;
    const int id = blockIdx.x;               // [0, 1024)
    const int b  = id & 7;                   // XCD-aware swizzle
    const int ho = (id >> 3) & 63;
    const int mh = id >> 9;                  // pos half 0/1

    const int lane = t & 63;
    const int wv   = t >> 6;                 // wave id 0..3
    const int lr   = lane & 15;              // MFMA row/col part
    const int lk   = (lane >> 4) * 8;        // MFMA k offset (shorts)
    const int q    = lane >> 4;              // D row quad

    const unsigned short* xb0 = xt + (size_t)b * (Hn * Wn * Cn);
    const short8 zz = {0, 0, 0, 0, 0, 0, 0, 0};

    // ---- P0: offset-conv GEMM for this half-row (bit-identical to R7) ----
    {
        const int cg = wv >> 1;              // conv/deform group
        const int nh = wv & 1;               // n-tile (oc 16-block)
        const int oc_l = nh * 16 + lr;
        float bias = (oc_l < 27) ? ob[cg * 27 + oc_l] : 0.f;
        f32x4 oacc[2];
        oacc[0] = (f32x4){bias, bias, bias, bias};
        oacc[1] = (f32x4){bias, bias, bias, bias};

        const unsigned short* xb = xb0 + cg * Cgn;
        const unsigned short* wf = owf + (size_t)cg * 18432;

        for (int tap = 0; tap < 9; ++tap) {
            int ky = tap / 3, kx = tap - ky * 3;
            int y = ho - 2 + 2 * ky;
            if (y < 0 || y >= Hn) continue;  // wave-uniform skip (zero pad)
#pragma unroll
            for (int ch = 0; ch < 2; ++ch) {
                int kssl = tap * 2 + ch;
                short8 bv = *(const short8*)&wf[(size_t)kssl * 1024 + nh * 512 + lane * 8];
#pragma unroll
                for (int mt = 0; mt < 2; ++mt) {
                    int wo = mh * 32 + mt * 16 + lr;
                    int xc = wo - 2 + 2 * kx;
                    bool vx = (xc >= 0) & (xc < Wn);
                    int xcc = min(max(xc, 0), Wn - 1);
                    short8 av = *(const short8*)&xb[((size_t)y * Wn + xcc) * Cn + ch * 32 + lk];
                    av = vx ? av : zz;
                    oacc[mt] = __builtin_amdgcn_mfma_f32_16x16x32_bf16(av, bv, oacc[mt], 0, 0, 0);
                }
            }
        }
        if (oc_l < 27) {
            int c54 = cg * 27 + oc_l;
#pragma unroll
            for (int mt = 0; mt < 2; ++mt)
#pragma unroll
                for (int r = 0; r < 4; ++r)
                    s_om[c54 * OMP + mt * 16 + q * 4 + r] = f2bf(oacc[mt][r]);
        }
    }
    __syncthreads();

    // ---- P1: sampling params for all (gk, pos) of this half-row ----
    for (int e = t; e < 18 * 32; e += 256) {
        int pos = e & 31;
        int wo  = mh * 32 + pos;
        int gk  = e >> 5;
        int g  = gk / 9, k = gk - g * 9;
        int ky = k / 3,  kx = k - ky * 3;
        float offy = bf2f(s_om[(g * 18 + k * 2 + 0) * OMP + pos]);
        float offx = bf2f(s_om[(g * 18 + k * 2 + 1) * OMP + pos]);
        float mk   = bf2f(s_om[(36 + g * 9 + k) * OMP + pos]);
        mk = 2.0f / (1.0f + __expf(-mk));

        float py = offy + (float)(ky * 2 + ho - 2);
        float px = offx + (float)(kx * 2 + wo - 2);
        float fy = floorf(py), fx = floorf(px);
        int   y0 = (int)fy,    x0 = (int)fx;
        float wy = py - fy,    wx = px - fx;

        bool vy0 = (y0 >= 0) & (y0 < Hn);
        bool vy1 = (y0 + 1 >= 0) & (y0 + 1 < Hn);
        bool vx0 = (x0 >= 0) & (x0 < Wn);
        bool vx1 = (x0 + 1 >= 0) & (x0 + 1 < Wn);
        float4 cw;
        cw.x = (vy0 & vx0) ? (1.f - wy) * (1.f - wx) * mk : 0.f;
        cw.y = (vy0 & vx1) ? (1.f - wy) * wx * mk : 0.f;
        cw.z = (vy1 & vx0) ? wy * (1.f - wx) * mk : 0.f;
        cw.w = (vy1 & vx1) ? wy * wx * mk : 0.f;

        int y0c = min(max(y0, 0), Hn - 1);
        int y1c = min(max(y0 + 1, 0), Hn - 1);
        int x0c = min(max(x0, 0), Wn - 1);
        int x1c = min(max(x0 + 1, 0), Wn - 1);
        s_cw[gk][pos] = cw;
        s_pk[gk][pos] = y0c | (y1c << 8) | (x0c << 16) | (x1c << 24);
    }
    __syncthreads();

    // ---- P2: gather + MFMA loop (R8-proven) ----
    const int pos = t >> 3;                  // gather: position 0..31
    const int cq  = (t & 7) * 8;             // gather: 8-ch chunk (group-local)

    f32x4 acc[2][2];
#pragma unroll
    for (int mt = 0; mt < 2; ++mt)
#pragma unroll
        for (int nt = 0; nt < 2; ++nt) acc[mt][nt] = (f32x4){0.f, 0.f, 0.f, 0.f};

    for (int gk = 0; gk < 18; ++gk) {
        // ---- B fragments, lane-contiguous from wt2 (L2-hot) ----
        const unsigned short* wf = wt2 + (size_t)gk * 8192;
        short8 bfr[2][2];
#pragma unroll
        for (int ks = 0; ks < 2; ++ks)
#pragma unroll
            for (int nt = 0; nt < 2; ++nt)
                bfr[ks][nt] = *(const short8*)&wf[(size_t)(ks * 8 + wv * 2 + nt) * 512 + lane * 8];

        // ---- gather: 4 corners x 8 channels, coalesced NHWC loads ----
        {
            const int g = gk / 9;
            float4 cw = s_cw[gk][pos];
            int pk  = s_pk[gk][pos];
            int y0c = pk & 255, y1c = (pk >> 8) & 255;
            int x0c = (pk >> 16) & 255, x1c = (pk >> 24) & 255;
            const unsigned short* xb = xb0 + g * Cgn + cq;
            short8 a00 = *(const short8*)&xb[((size_t)y0c * Wn + x0c) * Cn];
            short8 a01 = *(const short8*)&xb[((size_t)y0c * Wn + x1c) * Cn];
            short8 a10 = *(const short8*)&xb[((size_t)y1c * Wn + x0c) * Cn];
            short8 a11 = *(const short8*)&xb[((size_t)y1c * Wn + x1c) * Cn];
            short8 h0;
#pragma unroll
            for (int i = 0; i < 8; ++i) {
                float v = cw.x * bf2f((unsigned short)a00[i]) +
                          cw.y * bf2f((unsigned short)a01[i]) +
                          cw.z * bf2f((unsigned short)a10[i]) +
                          cw.w * bf2f((unsigned short)a11[i]);
                h0[i] = (short)f2bf(v);
            }
            *(short8*)&s_val[pos * PITCH + cq] = h0;
        }
        __syncthreads();

        // ---- 2 K-steps of MFMA ----
#pragma unroll
        for (int ks = 0; ks < 2; ++ks) {
            short8 af[2];
#pragma unroll
            for (int mt = 0; mt < 2; ++mt)
                af[mt] = *(const short8*)&s_val[(mt * 16 + lr) * PITCH + ks * 32 + lk];
#pragma unroll
            for (int mt = 0; mt < 2; ++mt)
#pragma unroll
                for (int nt = 0; nt < 2; ++nt)
                    acc[mt][nt] = __builtin_amdgcn_mfma_f32_16x16x32_bf16(
                        af[mt], bfr[ks][nt], acc[mt][nt], 0, 0, 0);
        }
        __syncthreads();
    }

    // ---- epilogue: D col = oc, row = pos (within this 32-pos half) ----
#pragma unroll
    for (int mt = 0; mt < 2; ++mt)
#pragma unroll
        for (int nt = 0; nt < 2; ++nt) {
            int oc = wv * 32 + nt * 16 + lr;
            int p0 = mh * 32 + mt * 16 + q * 4;
            float4 v = {acc[mt][nt][0], acc[mt][nt][1], acc[mt][nt][2], acc[mt][nt][3]};
            *(float4*)&out[(((size_t)b * Con + oc) * HOn + ho) * WOn + p0] = v;
        }
}

// ---------------------------------------------------------------------------
extern "C" void kernel_launch(void* const* d_in, const int* in_sizes, int n_in,
                              void* d_out, int out_size, void* d_ws, size_t ws_size,
                              hipStream_t stream) {
    const float* x  = (const float*)d_in[0];   // [8,128,64,64]
    const float* ow = (const float*)d_in[1];   // [54,64,3,3]
    const float* ob = (const float*)d_in[2];   // [54]
    const float* w  = (const float*)d_in[3];   // [128,128,3,3]
    float* out = (float*)d_out;                // [8,128,64,64]

    // ws: x_t bf16 8,388,608 | wt2 294,912 | owf 73,728
    unsigned short* xt  = (unsigned short*)d_ws;
    unsigned short* wt2 = (unsigned short*)((char*)d_ws + 8388608);
    unsigned short* owf = (unsigned short*)((char*)d_ws + 8388608 + 294912);

    hipLaunchKernelGGL(prep, dim3(1232), dim3(256), 0, stream,
                       x, w, ow, xt, wt2, owf);
    hipLaunchKernelGGL(dcn_fused, dim3(1024), dim3(256), 0, stream,
                       xt, owf, ob, wt2, out);
}